// Round 13
// baseline (567.954 us; speedup 1.0000x reference)
//
#include <hip/hip_runtime.h>
#include <hip/hip_fp16.h>

#define N_NODES 100000
#define N_EDGES 1200000
#define GRAPHS 128
#define EPSBN 1e-5f
#define NSHARD 8
#define SH_NODES 12500   // N_NODES / NSHARD exact

// ---------------- fused: XCD-sharded CSR build (blocks 0..2047) + BN stats on x (2048..2559) ----
// build is latency/atomic-bound (HBM 15%, VALU 3%) -> the independent 25.6MB stats stream
// rides along nearly free. No data deps between the halves.

__global__ __launch_bounds__(256) void k_build_stats(const int* __restrict__ src,
                                                     const int* __restrict__ dst,
                                                     int* __restrict__ cnt,
                                                     int* __restrict__ deg,
                                                     int* __restrict__ ecsr,
                                                     const float* __restrict__ x,
                                                     float* __restrict__ sums) {
    int t = threadIdx.x;
    if (blockIdx.x < 2048) {
        int shard = blockIdx.x & (NSHARD - 1);
        int lo = shard * SH_NODES, hi = lo + SH_NODES;
        for (int e = (blockIdx.x >> 3) * 256 + t; e < N_EDGES; e += 65536) {
            int s = __builtin_nontemporal_load(&src[e]);
            int d = __builtin_nontemporal_load(&dst[e]);
            if (s >= lo && s < hi) atomicAdd(&deg[s], 1);
            if (d >= lo && d < hi) {
                int p = atomicAdd(&cnt[d], 1);
                ecsr[(d << 6) + p] = s;
            }
        }
    } else {
        int bid = blockIdx.x - 2048;   // 0..511
        const float4* x4 = (const float4*)x;
        int q = t & 15, rg = t >> 4;
        float4 s = {0.f, 0.f, 0.f, 0.f}, s2 = {0.f, 0.f, 0.f, 0.f};
        for (int r = bid * 16 + rg; r < N_NODES; r += 512 * 16) {
            float4 v = x4[r * 16 + q];
            s.x += v.x; s.y += v.y; s.z += v.z; s.w += v.w;
            s2.x += v.x * v.x; s2.y += v.y * v.y; s2.z += v.z * v.z; s2.w += v.w * v.w;
        }
        __shared__ float red[2][16][64];
        red[0][rg][q * 4 + 0] = s.x;  red[0][rg][q * 4 + 1] = s.y;
        red[0][rg][q * 4 + 2] = s.z;  red[0][rg][q * 4 + 3] = s.w;
        red[1][rg][q * 4 + 0] = s2.x; red[1][rg][q * 4 + 1] = s2.y;
        red[1][rg][q * 4 + 2] = s2.z; red[1][rg][q * 4 + 3] = s2.w;
        __syncthreads();
        if (t < 64) {
            float a = 0.f, b = 0.f;
#pragma unroll
            for (int k = 0; k < 16; k++) { a += red[0][k][t]; b += red[1][k][t]; }
            atomicAdd(&sums[t], a);
            atomicAdd(&sums[64 + t], b);
        }
    }
}

// ---------------- fused: dis (blocks 0..390) + BN fold for feature layer (block 391) ----------------

__global__ __launch_bounds__(256) void k_dis_fold(const int* __restrict__ deg,
                       float* __restrict__ dis,
                       const float* __restrict__ sums, const float* __restrict__ g,
                       const float* __restrict__ b, const float* __restrict__ W,
                       const float* __restrict__ bias_in,
                       float* __restrict__ Wout, float* __restrict__ bout) {
    int t = threadIdx.x;
    if (blockIdx.x < 391) {
        int i = blockIdx.x * 256 + t;
        if (i < N_NODES) dis[i] = rsqrtf((float)deg[i] + 1.0f);   // +1 self-loop
    } else {
        __shared__ float a[64], cc[64];
        if (t < 64) {
            float mu = sums[t] * (1.0f / N_NODES);
            float var = sums[64 + t] * (1.0f / N_NODES) - mu * mu;
            float av = g[t] * rsqrtf(var + EPSBN);
            a[t] = av;
            cc[t] = b[t] - mu * av;
        }
        __syncthreads();
        for (int i = t; i < 4096; i += 256) Wout[i] = a[i >> 6] * W[i];
        if (t < 64) {
            float acc = bias_in[t];
            for (int k = 0; k < 64; k++) acc += cc[k] * W[k * 64 + t];
            bout[t] = acc;
        }
    }
}

// ---------------- fused: feature GEMM (blocks 0..2047) + sigma (2048..3071) ----------------
// gemm2 is BW-bound on x; sigma is a latency-bound gather -> overlaps inside it.
// (256,4) proven spill-free for the gemm2 body; (256,8) spills — twice confirmed.

__global__ __launch_bounds__(256, 4) void k_sigma_gemm2(const float* __restrict__ X,
                        const float* __restrict__ W,
                        const float* __restrict__ bias, const float* __restrict__ dis,
                        __half* __restrict__ U, float* __restrict__ sums,
                        const int* __restrict__ cnt, const int* __restrict__ ecsr,
                        float* __restrict__ sigma) {
    __shared__ float wlds[64][64];
    __shared__ float xs[16][64];
    int t = threadIdx.x;
    if (blockIdx.x < 2048) {
        int j = t & 63;
        int rg = t >> 6;
        for (int i = t; i < 4096; i += 256) wlds[i >> 6][i & 63] = W[i];
        float bj = bias[j];
        __syncthreads();
        float s_sum = 0.f, s_sq = 0.f;
        for (int base = blockIdx.x * 16; base < N_NODES; base += 2048 * 16) {
            ((float4*)xs)[t] = ((const float4*)(X + base * 64))[t];   // wave-private rows
            int r0 = rg * 4;
            float a0 = bj, a1 = bj, a2 = bj, a3 = bj;
            const float4* x0 = (const float4*)xs[r0 + 0];
            const float4* x1 = (const float4*)xs[r0 + 1];
            const float4* x2 = (const float4*)xs[r0 + 2];
            const float4* x3 = (const float4*)xs[r0 + 3];
#pragma unroll
            for (int q4 = 0; q4 < 16; q4++) {
                float w0 = wlds[q4 * 4 + 0][j], w1 = wlds[q4 * 4 + 1][j];
                float w2 = wlds[q4 * 4 + 2][j], w3 = wlds[q4 * 4 + 3][j];
                float4 v0 = x0[q4]; a0 += v0.x * w0 + v0.y * w1 + v0.z * w2 + v0.w * w3;
                float4 v1 = x1[q4]; a1 += v1.x * w0 + v1.y * w1 + v1.z * w2 + v1.w * w3;
                float4 v2 = x2[q4]; a2 += v2.x * w0 + v2.y * w1 + v2.z * w2 + v2.w * w3;
                float4 v3 = x3[q4]; a3 += v3.x * w0 + v3.y * w1 + v3.z * w2 + v3.w * w3;
            }
            a0 = fmaxf(a0, 0.f); a1 = fmaxf(a1, 0.f);
            a2 = fmaxf(a2, 0.f); a3 = fmaxf(a3, 0.f);
            int nb = base + r0;
            U[(nb + 0) * 64 + j] = __float2half_rn(a0 * dis[nb + 0]);
            U[(nb + 1) * 64 + j] = __float2half_rn(a1 * dis[nb + 1]);
            U[(nb + 2) * 64 + j] = __float2half_rn(a2 * dis[nb + 2]);
            U[(nb + 3) * 64 + j] = __float2half_rn(a3 * dis[nb + 3]);
            s_sum += a0 + a1 + a2 + a3;
            s_sq += a0 * a0 + a1 * a1 + a2 * a2 + a3 * a3;
        }
        __syncthreads();
        xs[rg][j] = s_sum;
        xs[4 + rg][j] = s_sq;
        __syncthreads();
        if (t < 64) {
            atomicAdd(&sums[t], xs[0][t] + xs[1][t] + xs[2][t] + xs[3][t]);
            atomicAdd(&sums[64 + t], xs[4][t] + xs[5][t] + xs[6][t] + xs[7][t]);
        }
    } else {
        int bid = blockIdx.x - 2048;   // 0..1023
        int lane = t & 63;
        int wid = t >> 6;
        for (int node = bid * 4 + wid; node < N_NODES; node += 1024 * 4) {
            int m = cnt[node];
            int sraw = ecsr[(node << 6) + lane];
            float dd = dis[node];
            int sL = (lane < m) ? sraw : 0;
            float v = (lane < m) ? dis[sL] : 0.f;
#pragma unroll
            for (int d = 1; d <= 32; d <<= 1) v += __shfl_xor(v, d, 64);
            if (lane == 0) sigma[node] = dd * (v + dd);
        }
    }
}

// ---------------- fused agg+GEMM with in-kernel BN fold (sigma correction) ----------------
// Phase A: unrolled PREDICATED gathers extended to 32 slots (was 16) — kills the rolled
// serial tail loop hit by ~10% of rows (Poisson-12 P(m>16)≈0.10, each ~1600cy serial).
// P(m>32)≈1e-6: serial fallback kept for safety, essentially never taken. Masked extra
// gathers hit u2[0] (L1 broadcast) — near-free. Round-11 lesson: unrolled-predicated
// beats trimmed-sequential in this latency-bound regime. (256,4) spill-free.

__global__ __launch_bounds__(256, 4) void k_aggemm(const __half* __restrict__ u,
                        const float* __restrict__ dis, const float* __restrict__ sigma,
                        const int* __restrict__ cnt, const int* __restrict__ ecsr,
                        const float* __restrict__ sums_in, const float* __restrict__ bng,
                        const float* __restrict__ bnb,
                        const float* __restrict__ W, const float* __restrict__ bias,
                        __half* __restrict__ uout, float* __restrict__ hout, int last,
                        float* __restrict__ sums_out, int do_stats) {
    const __half2* u2 = (const __half2*)u;
    int t = threadIdx.x;
    int j = t & 63;           // lane; also output column in GEMM phase
    int wid = t >> 6;
    int g = j >> 5, c = j & 31;
    __shared__ float wlds[64][64];
    __shared__ float xs[16][64];   // wave w owns rows 4w..4w+3 (wave-private); prologue: xs[0]=aa, xs[1]=ccs
    if (t < 64) {
        float mu = sums_in[t] * (1.0f / N_NODES);
        float var = sums_in[64 + t] * (1.0f / N_NODES) - mu * mu;
        float av = bng[t] * rsqrtf(var + EPSBN);
        xs[0][t] = av;                 // aa
        xs[1][t] = bnb[t] - mu * av;   // ccs
    }
    __syncthreads();
    for (int i = t; i < 4096; i += 256) wlds[i >> 6][i & 63] = W[i] * xs[0][i >> 6];
    float cb = 0.f;
#pragma unroll 8
    for (int q = 0; q < 64; q++) cb += xs[1][q] * W[q * 64 + j];
    float bj = bias[j];
    __syncthreads();
    float s_sum = 0.f, s_sq = 0.f;
    for (int base = blockIdx.x * 16; base < N_NODES; base += gridDim.x * 16) {
        int r0 = wid * 4;
        int nb = base + r0;
        // ---- hoisted independent loads for all 4 rows ----
        int mm[4], srw[4];
        float dvals[4], svals[4];
        __half2 selfs[4];
#pragma unroll
        for (int r = 0; r < 4; r++) {
            mm[r] = cnt[nb + r];
            srw[r] = ecsr[((nb + r) << 6) + j];
            dvals[r] = dis[nb + r];
            svals[r] = sigma[nb + r];
            selfs[r] = u2[(nb + r) * 32 + c];
        }
        // ---- phase A: row-paired, 32-slot unrolled predicated gathers ----
#pragma unroll
        for (int rp = 0; rp < 2; rp++) {
            int ra = 2 * rp, rb = 2 * rp + 1;
            int ma = mm[ra], mb = mm[rb];
            int sLa = (j < ma) ? srw[ra] : 0;
            int sLb = (j < mb) ? srw[rb] : 0;
            float axa = 0.f, aya = 0.f, axb = 0.f, ayb = 0.f;
#pragma unroll
            for (int k = 0; k < 16; k++) {
                int e = 2 * k + g;
                int sEa = __shfl(sLa, e, 64);
                int sEb = __shfl(sLb, e, 64);
                float wa = (e < ma) ? 1.0f : 0.0f;
                float wb = (e < mb) ? 1.0f : 0.0f;
                float2 fa = __half22float2(u2[sEa * 32 + c]);
                float2 fb = __half22float2(u2[sEb * 32 + c]);
                axa += wa * fa.x; aya += wa * fa.y;
                axb += wb * fb.x; ayb += wb * fb.y;
            }
            if (ma > 32) {
                for (int e = 32 + g; e < ma; e += 2) {
                    int sE = __shfl(sLa, e, 64);
                    float2 f = __half22float2(u2[sE * 32 + c]);
                    axa += f.x; aya += f.y;
                }
            }
            if (mb > 32) {
                for (int e = 32 + g; e < mb; e += 2) {
                    int sE = __shfl(sLb, e, 64);
                    float2 f = __half22float2(u2[sE * 32 + c]);
                    axb += f.x; ayb += f.y;
                }
            }
            axa += __shfl_xor(axa, 32, 64); aya += __shfl_xor(aya, 32, 64);
            axb += __shfl_xor(axb, 32, 64); ayb += __shfl_xor(ayb, 32, 64);
            if (g == 0) {
                float2 sfa = __half22float2(selfs[ra]);
                float2 sfb = __half22float2(selfs[rb]);
                float da = dvals[ra], db = dvals[rb];
                xs[r0 + ra][2 * c + 0] = da * (axa + sfa.x);
                xs[r0 + ra][2 * c + 1] = da * (aya + sfa.y);
                xs[r0 + rb][2 * c + 0] = db * (axb + sfb.x);
                xs[r0 + rb][2 * c + 1] = db * (ayb + sfb.y);
            }
        }
        // ---- phase B: GEMM + sigma correction (wave-private LDS, W from LDS) ----
        float a0 = bj + svals[0] * cb, a1 = bj + svals[1] * cb;
        float a2 = bj + svals[2] * cb, a3 = bj + svals[3] * cb;
        const float4* x0 = (const float4*)xs[r0 + 0];
        const float4* x1 = (const float4*)xs[r0 + 1];
        const float4* x2 = (const float4*)xs[r0 + 2];
        const float4* x3 = (const float4*)xs[r0 + 3];
#pragma unroll
        for (int q4 = 0; q4 < 16; q4++) {
            float w0 = wlds[q4 * 4 + 0][j], w1 = wlds[q4 * 4 + 1][j];
            float w2 = wlds[q4 * 4 + 2][j], w3 = wlds[q4 * 4 + 3][j];
            float4 v0 = x0[q4]; a0 += v0.x * w0 + v0.y * w1 + v0.z * w2 + v0.w * w3;
            float4 v1 = x1[q4]; a1 += v1.x * w0 + v1.y * w1 + v1.z * w2 + v1.w * w3;
            float4 v2 = x2[q4]; a2 += v2.x * w0 + v2.y * w1 + v2.z * w2 + v2.w * w3;
            float4 v3 = x3[q4]; a3 += v3.x * w0 + v3.y * w1 + v3.z * w2 + v3.w * w3;
        }
        a0 = fmaxf(a0, 0.f); a1 = fmaxf(a1, 0.f);
        a2 = fmaxf(a2, 0.f); a3 = fmaxf(a3, 0.f);
        if (last) {
            hout[(nb + 0) * 64 + j] = a0;
            hout[(nb + 1) * 64 + j] = a1;
            hout[(nb + 2) * 64 + j] = a2;
            hout[(nb + 3) * 64 + j] = a3;
        } else {
            uout[(nb + 0) * 64 + j] = __float2half_rn(a0 * dvals[0]);
            uout[(nb + 1) * 64 + j] = __float2half_rn(a1 * dvals[1]);
            uout[(nb + 2) * 64 + j] = __float2half_rn(a2 * dvals[2]);
            uout[(nb + 3) * 64 + j] = __float2half_rn(a3 * dvals[3]);
        }
        if (do_stats) {
            s_sum += a0 + a1 + a2 + a3;
            s_sq += a0 * a0 + a1 * a1 + a2 * a2 + a3 * a3;
        }
    }
    if (do_stats) {
        __syncthreads();
        xs[wid][j] = s_sum;
        xs[4 + wid][j] = s_sq;
        __syncthreads();
        if (t < 64) {
            atomicAdd(&sums_out[t], xs[0][t] + xs[1][t] + xs[2][t] + xs[3][t]);
            atomicAdd(&sums_out[64 + t], xs[4][t] + xs[5][t] + xs[6][t] + xs[7][t]);
        }
    }
}

// ---------------- global_add_pool: 4 blocks per graph, atomic partials into zeroed hg ----------------

__global__ __launch_bounds__(256) void k_pool(const float* __restrict__ h, const int* __restrict__ batch,
                       float* __restrict__ hg) {
    int g = blockIdx.x >> 2, q3 = blockIdx.x & 3;
    int lo = 0, hi = N_NODES;
    while (lo < hi) { int m = (lo + hi) >> 1; if (batch[m] < g) lo = m + 1; else hi = m; }
    int start = lo;
    lo = start; hi = N_NODES;
    while (lo < hi) { int m = (lo + hi) >> 1; if (batch[m] < g + 1) lo = m + 1; else hi = m; }
    int end = lo;
    int len = end - start;
    int c0 = start + ((len * q3) >> 2);
    int c1 = start + ((len * (q3 + 1)) >> 2);
    int c = threadIdx.x & 63, rg = threadIdx.x >> 6;
    float s = 0.f;
    for (int r = c0 + rg; r < c1; r += 4) s += h[r * 64 + c];
    __shared__ float ls[4][64];
    ls[rg][c] = s;
    __syncthreads();
    if (rg == 0) atomicAdd(&hg[g * 64 + c], ls[0][c] + ls[1][c] + ls[2][c] + ls[3][c]);
}

// ---------------- tail: BN-fc stats from hg -> BN -> FC+relu -> BN -> classifier -> log_softmax ----------------

__global__ __launch_bounds__(512) void k_tail(const float* __restrict__ hg_in,
                       const float* __restrict__ g1, const float* __restrict__ b1,
                       const float* __restrict__ Wfc, const float* __restrict__ bfc,
                       const float* __restrict__ g2, const float* __restrict__ b2,
                       const float* __restrict__ Wcls, const float* __restrict__ bcls,
                       float* __restrict__ out) {
    __shared__ float hgn[8192];
    __shared__ float h2[8192];
    __shared__ float red[2][8][64];
    __shared__ float a[64], cc[64];
    __shared__ float Wc[640];
    __shared__ float logits[1280];
    __shared__ float lse[128];
    int t = threadIdx.x;
    int j = t & 63;
    int w = t >> 6;

    // BN-fc stats over the 128 pooled rows (computed in-kernel)
    {
        float su = 0.f, sq = 0.f;
#pragma unroll
        for (int gg = 0; gg < 16; gg++) {
            float v = hg_in[(w * 16 + gg) * 64 + j];
            su += v; sq += v * v;
        }
        red[0][w][j] = su; red[1][w][j] = sq;
    }
    for (int i = t; i < 640; i += 512) Wc[i] = Wcls[i];
    __syncthreads();
    if (t < 64) {
        float su = 0.f, sq = 0.f;
#pragma unroll
        for (int k = 0; k < 8; k++) { su += red[0][k][t]; sq += red[1][k][t]; }
        float mu = su * (1.f / 128.f);
        float var = sq * (1.f / 128.f) - mu * mu;
        float av = g1[t] * rsqrtf(var + EPSBN);
        a[t] = av; cc[t] = b1[t] - mu * av;
    }
    __syncthreads();
    for (int i = t; i < 8192; i += 512) hgn[i] = hg_in[i] * a[i & 63] + cc[i & 63];

    float wreg[64];
#pragma unroll
    for (int q = 0; q < 64; q++) wreg[q] = Wfc[q * 64 + j];
    float bj = bfc[j];
    __syncthreads();

    float acc[16];
#pragma unroll
    for (int r = 0; r < 16; r++) acc[r] = bj;
    const float4* hgn4 = (const float4*)hgn;
#pragma unroll
    for (int q4 = 0; q4 < 16; q4++) {
#pragma unroll
        for (int r = 0; r < 16; r++) {
            float4 hv = hgn4[(w * 16 + r) * 16 + q4];
            acc[r] += hv.x * wreg[q4 * 4 + 0] + hv.y * wreg[q4 * 4 + 1]
                    + hv.z * wreg[q4 * 4 + 2] + hv.w * wreg[q4 * 4 + 3];
        }
    }
    float s = 0.f, s2 = 0.f;
#pragma unroll
    for (int r = 0; r < 16; r++) {
        float v = fmaxf(acc[r], 0.f);
        h2[(w * 16 + r) * 64 + j] = v;
        s += v; s2 += v * v;
    }
    red[0][w][j] = s; red[1][w][j] = s2;
    __syncthreads();

    if (t < 64) {
        float su = 0.f, sq = 0.f;
#pragma unroll
        for (int k = 0; k < 8; k++) { su += red[0][k][t]; sq += red[1][k][t]; }
        float mu = su * (1.f / 128.f);
        float var = sq * (1.f / 128.f) - mu * mu;
        float av = g2[t] * rsqrtf(var + EPSBN);
        a[t] = av; cc[t] = b2[t] - mu * av;
    }
    __syncthreads();
    for (int i = t; i < 8192; i += 512) h2[i] = h2[i] * a[i & 63] + cc[i & 63];
    __syncthreads();

    for (int idx = t; idx < 1280; idx += 512) {
        int row = idx / 10, o = idx - row * 10;
        float v = bcls[o];
#pragma unroll
        for (int q = 0; q < 64; q++) v += h2[row * 64 + q] * Wc[q * 10 + o];
        logits[idx] = v;
    }
    __syncthreads();
    if (t < 128) {
        float mx = -1e30f;
#pragma unroll
        for (int o = 0; o < 10; o++) mx = fmaxf(mx, logits[t * 10 + o]);
        float se = 0.f;
#pragma unroll
        for (int o = 0; o < 10; o++) se += expf(logits[t * 10 + o] - mx);
        lse[t] = mx + logf(se);
    }
    __syncthreads();
    for (int idx = t; idx < 1280; idx += 512) out[idx] = logits[idx] - lse[idx / 10];
}

// ---------------- launcher ----------------

extern "C" void kernel_launch(void* const* d_in, const int* in_sizes, int n_in,
                              void* d_out, int out_size, void* d_ws, size_t ws_size,
                              hipStream_t stream) {
    const float* x         = (const float*)d_in[0];
    const int*   ei        = (const int*)  d_in[1];
    const int*   batch     = (const int*)  d_in[2];
    const float* bn_feat_g = (const float*)d_in[3];
    const float* bn_feat_b = (const float*)d_in[4];
    const float* W_feat    = (const float*)d_in[5];
    const float* b_feat    = (const float*)d_in[6];
    const float* conv_bn_g = (const float*)d_in[7];
    const float* conv_bn_b = (const float*)d_in[8];
    const float* conv_W    = (const float*)d_in[9];
    const float* conv_b    = (const float*)d_in[10];
    const float* bn_fc_g   = (const float*)d_in[11];
    const float* bn_fc_b   = (const float*)d_in[12];
    const float* W_fc      = (const float*)d_in[13];
    const float* b_fc      = (const float*)d_in[14];
    const float* bn_hid_g  = (const float*)d_in[15];
    const float* bn_hid_b  = (const float*)d_in[16];
    const float* W_cls     = (const float*)d_in[17];
    const float* b_cls     = (const float*)d_in[18];
    float* out = (float*)d_out;

    float* ws    = (float*)d_ws;
    float* hbuf  = ws;                          // 6,400,000 f (final layer h only)
    __half* u_a  = (__half*)(ws + 6400000);     // 6.4M halves
    __half* u_b  = (__half*)(ws + 9600000);     // 6.4M halves
    float* dis   = ws + 12800000;               // 100,000 f
    float* sigma = ws + 12900000;               // 100,000 f
    float* Wt    = ws + 13000000;               // 4096 f
    float* bt    = Wt + 4096;                   // 64 f
    float* hg    = bt + 64;                     // 8192 f
    float* sums  = hg + 8192;                   // 640 f (sx, s0, s1, s2)
    int*   cnt   = (int*)(sums + 640);          // 100,000 i
    int*   ecsr  = cnt + 100000;                // 6,400,000 i
    int*   deg   = (int*)u_b;                   // 100,000 i scratch; dead before u_b written

    float* sx = sums;
    float* s0 = sums + 128;
    float* s1 = sums + 256;
    float* s2 = sums + 384;

    const int* srcp = ei;
    const int* dstp = ei + N_EDGES;

    // zero hg + sums + cnt in one contiguous memset; deg lives in u_b scratch
    hipMemsetAsync(hg, 0, (8192 + 640 + 100000) * sizeof(float), stream);
    hipMemsetAsync(deg, 0, 100000 * sizeof(int), stream);

    // fused pipeline: [build || stats] -> [dis + fold] -> [gemm2 || sigma]
    k_build_stats<<<2560, 256, 0, stream>>>(srcp, dstp, cnt, deg, ecsr, x, sx);
    k_dis_fold<<<392, 256, 0, stream>>>(deg, dis, sx, bn_feat_g, bn_feat_b,
                                        W_feat, b_feat, Wt, bt);
    k_sigma_gemm2<<<3072, 256, 0, stream>>>(x, Wt, bt, dis, u_a, s0, cnt, ecsr, sigma);

    // 3 GCN conv layers: aggemm with in-kernel BN fold + sigma correction, u double-buffered
    k_aggemm<<<2048, 256, 0, stream>>>(u_a, dis, sigma, cnt, ecsr,
                                       s0, conv_bn_g + 0, conv_bn_b + 0,
                                       conv_W + 0, conv_b + 0,
                                       u_b, nullptr, 0, s1, 1);
    k_aggemm<<<2048, 256, 0, stream>>>(u_b, dis, sigma, cnt, ecsr,
                                       s1, conv_bn_g + 64, conv_bn_b + 64,
                                       conv_W + 4096, conv_b + 64,
                                       u_a, nullptr, 0, s2, 1);
    k_aggemm<<<2048, 256, 0, stream>>>(u_a, dis, sigma, cnt, ecsr,
                                       s2, conv_bn_g + 128, conv_bn_b + 128,
                                       conv_W + 8192, conv_b + 128,
                                       nullptr, hbuf, 1, nullptr, 0);

    // pooling + tail (BN-fc stats computed inside k_tail)
    k_pool<<<4 * GRAPHS, 256, 0, stream>>>(hbuf, batch, hg);
    k_tail<<<1, 512, 0, stream>>>(hg, bn_fc_g, bn_fc_b, W_fc, b_fc,
                                  bn_hid_g, bn_hid_b, W_cls, b_cls, out);
}

// Round 14
// 519.704 us; speedup vs baseline: 1.0928x; 1.0928x over previous
//
#include <hip/hip_runtime.h>
#include <hip/hip_fp16.h>

#define N_NODES 100000
#define N_EDGES 1200000
#define GRAPHS 128
#define EPSBN 1e-5f
#define NSHARD 8
#define SH_NODES 12500   // N_NODES / NSHARD exact

// ---------------- fused: XCD-sharded CSR build (blocks 0..2047) + BN stats on x (2048..2559) ----

__global__ __launch_bounds__(256) void k_build_stats(const int* __restrict__ src,
                                                     const int* __restrict__ dst,
                                                     int* __restrict__ cnt,
                                                     int* __restrict__ deg,
                                                     int* __restrict__ ecsr,
                                                     const float* __restrict__ x,
                                                     float* __restrict__ sums) {
    int t = threadIdx.x;
    if (blockIdx.x < 2048) {
        int shard = blockIdx.x & (NSHARD - 1);
        int lo = shard * SH_NODES, hi = lo + SH_NODES;
        for (int e = (blockIdx.x >> 3) * 256 + t; e < N_EDGES; e += 65536) {
            int s = __builtin_nontemporal_load(&src[e]);
            int d = __builtin_nontemporal_load(&dst[e]);
            if (s >= lo && s < hi) atomicAdd(&deg[s], 1);
            if (d >= lo && d < hi) {
                int p = atomicAdd(&cnt[d], 1);
                ecsr[(d << 6) + p] = s;
            }
        }
    } else {
        int bid = blockIdx.x - 2048;   // 0..511
        const float4* x4 = (const float4*)x;
        int q = t & 15, rg = t >> 4;
        float4 s = {0.f, 0.f, 0.f, 0.f}, s2 = {0.f, 0.f, 0.f, 0.f};
        for (int r = bid * 16 + rg; r < N_NODES; r += 512 * 16) {
            float4 v = x4[r * 16 + q];
            s.x += v.x; s.y += v.y; s.z += v.z; s.w += v.w;
            s2.x += v.x * v.x; s2.y += v.y * v.y; s2.z += v.z * v.z; s2.w += v.w * v.w;
        }
        __shared__ float red[2][16][64];
        red[0][rg][q * 4 + 0] = s.x;  red[0][rg][q * 4 + 1] = s.y;
        red[0][rg][q * 4 + 2] = s.z;  red[0][rg][q * 4 + 3] = s.w;
        red[1][rg][q * 4 + 0] = s2.x; red[1][rg][q * 4 + 1] = s2.y;
        red[1][rg][q * 4 + 2] = s2.z; red[1][rg][q * 4 + 3] = s2.w;
        __syncthreads();
        if (t < 64) {
            float a = 0.f, b = 0.f;
#pragma unroll
            for (int k = 0; k < 16; k++) { a += red[0][k][t]; b += red[1][k][t]; }
            atomicAdd(&sums[t], a);
            atomicAdd(&sums[64 + t], b);
        }
    }
}

// ---------------- fused: dis (blocks 0..390) + BN fold for feature layer (block 391) ----------------

__global__ __launch_bounds__(256) void k_dis_fold(const int* __restrict__ deg,
                       float* __restrict__ dis,
                       const float* __restrict__ sums, const float* __restrict__ g,
                       const float* __restrict__ b, const float* __restrict__ W,
                       const float* __restrict__ bias_in,
                       float* __restrict__ Wout, float* __restrict__ bout) {
    int t = threadIdx.x;
    if (blockIdx.x < 391) {
        int i = blockIdx.x * 256 + t;
        if (i < N_NODES) dis[i] = rsqrtf((float)deg[i] + 1.0f);   // +1 self-loop
    } else {
        __shared__ float a[64], cc[64];
        if (t < 64) {
            float mu = sums[t] * (1.0f / N_NODES);
            float var = sums[64 + t] * (1.0f / N_NODES) - mu * mu;
            float av = g[t] * rsqrtf(var + EPSBN);
            a[t] = av;
            cc[t] = b[t] - mu * av;
        }
        __syncthreads();
        for (int i = t; i < 4096; i += 256) Wout[i] = a[i >> 6] * W[i];
        if (t < 64) {
            float acc = bias_in[t];
            for (int k = 0; k < 64; k++) acc += cc[k] * W[k * 64 + t];
            bout[t] = acc;
        }
    }
}

// ---------------- fused: feature GEMM (blocks 0..2047) + sigma (2048..3071) ----------------

__global__ __launch_bounds__(256, 4) void k_sigma_gemm2(const float* __restrict__ X,
                        const float* __restrict__ W,
                        const float* __restrict__ bias, const float* __restrict__ dis,
                        __half* __restrict__ U, float* __restrict__ sums,
                        const int* __restrict__ cnt, const int* __restrict__ ecsr,
                        float* __restrict__ sigma) {
    __shared__ float wlds[64][64];
    __shared__ float xs[16][64];
    int t = threadIdx.x;
    if (blockIdx.x < 2048) {
        int j = t & 63;
        int rg = t >> 6;
        for (int i = t; i < 4096; i += 256) wlds[i >> 6][i & 63] = W[i];
        float bj = bias[j];
        __syncthreads();
        float s_sum = 0.f, s_sq = 0.f;
        for (int base = blockIdx.x * 16; base < N_NODES; base += 2048 * 16) {
            ((float4*)xs)[t] = ((const float4*)(X + base * 64))[t];   // wave-private rows
            int r0 = rg * 4;
            float a0 = bj, a1 = bj, a2 = bj, a3 = bj;
            const float4* x0 = (const float4*)xs[r0 + 0];
            const float4* x1 = (const float4*)xs[r0 + 1];
            const float4* x2 = (const float4*)xs[r0 + 2];
            const float4* x3 = (const float4*)xs[r0 + 3];
#pragma unroll
            for (int q4 = 0; q4 < 16; q4++) {
                float w0 = wlds[q4 * 4 + 0][j], w1 = wlds[q4 * 4 + 1][j];
                float w2 = wlds[q4 * 4 + 2][j], w3 = wlds[q4 * 4 + 3][j];
                float4 v0 = x0[q4]; a0 += v0.x * w0 + v0.y * w1 + v0.z * w2 + v0.w * w3;
                float4 v1 = x1[q4]; a1 += v1.x * w0 + v1.y * w1 + v1.z * w2 + v1.w * w3;
                float4 v2 = x2[q4]; a2 += v2.x * w0 + v2.y * w1 + v2.z * w2 + v2.w * w3;
                float4 v3 = x3[q4]; a3 += v3.x * w0 + v3.y * w1 + v3.z * w2 + v3.w * w3;
            }
            a0 = fmaxf(a0, 0.f); a1 = fmaxf(a1, 0.f);
            a2 = fmaxf(a2, 0.f); a3 = fmaxf(a3, 0.f);
            int nb = base + r0;
            U[(nb + 0) * 64 + j] = __float2half_rn(a0 * dis[nb + 0]);
            U[(nb + 1) * 64 + j] = __float2half_rn(a1 * dis[nb + 1]);
            U[(nb + 2) * 64 + j] = __float2half_rn(a2 * dis[nb + 2]);
            U[(nb + 3) * 64 + j] = __float2half_rn(a3 * dis[nb + 3]);
            s_sum += a0 + a1 + a2 + a3;
            s_sq += a0 * a0 + a1 * a1 + a2 * a2 + a3 * a3;
        }
        __syncthreads();
        xs[rg][j] = s_sum;
        xs[4 + rg][j] = s_sq;
        __syncthreads();
        if (t < 64) {
            atomicAdd(&sums[t], xs[0][t] + xs[1][t] + xs[2][t] + xs[3][t]);
            atomicAdd(&sums[64 + t], xs[4][t] + xs[5][t] + xs[6][t] + xs[7][t]);
        }
    } else {
        int bid = blockIdx.x - 2048;   // 0..1023
        int lane = t & 63;
        int wid = t >> 6;
        for (int node = bid * 4 + wid; node < N_NODES; node += 1024 * 4) {
            int m = cnt[node];
            int sraw = ecsr[(node << 6) + lane];
            float dd = dis[node];
            int sL = (lane < m) ? sraw : 0;
            float v = (lane < m) ? dis[sL] : 0.f;
#pragma unroll
            for (int d = 1; d <= 32; d <<= 1) v += __shfl_xor(v, d, 64);
            if (lane == 0) sigma[node] = dd * (v + dd);
        }
    }
}

// ---------------- fused agg+GEMM with in-kernel BN fold (sigma correction) ----------------
// Phase A: 16-slot row-paired predicated gathers (round-12 proven optimum). Round-11 showed
// fewer/serial regresses (latency chain); round-13 showed 32 slots regresses (2x issued
// gather BW against a 3x-oversubscribed per-XCD L2). (256,4) spill-free; (256,8) spills.

__global__ __launch_bounds__(256, 4) void k_aggemm(const __half* __restrict__ u,
                        const float* __restrict__ dis, const float* __restrict__ sigma,
                        const int* __restrict__ cnt, const int* __restrict__ ecsr,
                        const float* __restrict__ sums_in, const float* __restrict__ bng,
                        const float* __restrict__ bnb,
                        const float* __restrict__ W, const float* __restrict__ bias,
                        __half* __restrict__ uout, float* __restrict__ hout, int last,
                        float* __restrict__ sums_out, int do_stats) {
    const __half2* u2 = (const __half2*)u;
    int t = threadIdx.x;
    int j = t & 63;           // lane; also output column in GEMM phase
    int wid = t >> 6;
    int g = j >> 5, c = j & 31;
    __shared__ float wlds[64][64];
    __shared__ float xs[16][64];   // wave w owns rows 4w..4w+3 (wave-private); prologue: xs[0]=aa, xs[1]=ccs
    if (t < 64) {
        float mu = sums_in[t] * (1.0f / N_NODES);
        float var = sums_in[64 + t] * (1.0f / N_NODES) - mu * mu;
        float av = bng[t] * rsqrtf(var + EPSBN);
        xs[0][t] = av;                 // aa
        xs[1][t] = bnb[t] - mu * av;   // ccs
    }
    __syncthreads();
    for (int i = t; i < 4096; i += 256) wlds[i >> 6][i & 63] = W[i] * xs[0][i >> 6];
    float cb = 0.f;
#pragma unroll 8
    for (int q = 0; q < 64; q++) cb += xs[1][q] * W[q * 64 + j];
    float bj = bias[j];
    __syncthreads();
    float s_sum = 0.f, s_sq = 0.f;
    for (int base = blockIdx.x * 16; base < N_NODES; base += gridDim.x * 16) {
        int r0 = wid * 4;
        int nb = base + r0;
        // ---- hoisted independent loads for all 4 rows ----
        int mm[4], srw[4];
        float dvals[4], svals[4];
        __half2 selfs[4];
#pragma unroll
        for (int r = 0; r < 4; r++) {
            mm[r] = cnt[nb + r];
            srw[r] = ecsr[((nb + r) << 6) + j];
            dvals[r] = dis[nb + r];
            svals[r] = sigma[nb + r];
            selfs[r] = u2[(nb + r) * 32 + c];
        }
        // ---- phase A: row-paired interleaved 16-slot gathers ----
#pragma unroll
        for (int rp = 0; rp < 2; rp++) {
            int ra = 2 * rp, rb = 2 * rp + 1;
            int ma = mm[ra], mb = mm[rb];
            int sLa = (j < ma) ? srw[ra] : 0;
            int sLb = (j < mb) ? srw[rb] : 0;
            float axa = 0.f, aya = 0.f, axb = 0.f, ayb = 0.f;
#pragma unroll
            for (int k = 0; k < 8; k++) {
                int e = 2 * k + g;
                int sEa = __shfl(sLa, e, 64);
                int sEb = __shfl(sLb, e, 64);
                float wa = (e < ma) ? 1.0f : 0.0f;
                float wb = (e < mb) ? 1.0f : 0.0f;
                float2 fa = __half22float2(u2[sEa * 32 + c]);
                float2 fb = __half22float2(u2[sEb * 32 + c]);
                axa += wa * fa.x; aya += wa * fa.y;
                axb += wb * fb.x; ayb += wb * fb.y;
            }
            if (ma > 16) {
                for (int e = 16 + g; e < ma; e += 2) {
                    int sE = __shfl(sLa, e, 64);
                    float2 f = __half22float2(u2[sE * 32 + c]);
                    axa += f.x; aya += f.y;
                }
            }
            if (mb > 16) {
                for (int e = 16 + g; e < mb; e += 2) {
                    int sE = __shfl(sLb, e, 64);
                    float2 f = __half22float2(u2[sE * 32 + c]);
                    axb += f.x; ayb += f.y;
                }
            }
            axa += __shfl_xor(axa, 32, 64); aya += __shfl_xor(aya, 32, 64);
            axb += __shfl_xor(axb, 32, 64); ayb += __shfl_xor(ayb, 32, 64);
            if (g == 0) {
                float2 sfa = __half22float2(selfs[ra]);
                float2 sfb = __half22float2(selfs[rb]);
                float da = dvals[ra], db = dvals[rb];
                xs[r0 + ra][2 * c + 0] = da * (axa + sfa.x);
                xs[r0 + ra][2 * c + 1] = da * (aya + sfa.y);
                xs[r0 + rb][2 * c + 0] = db * (axb + sfb.x);
                xs[r0 + rb][2 * c + 1] = db * (ayb + sfb.y);
            }
        }
        // ---- phase B: GEMM + sigma correction (wave-private LDS, W from LDS) ----
        float a0 = bj + svals[0] * cb, a1 = bj + svals[1] * cb;
        float a2 = bj + svals[2] * cb, a3 = bj + svals[3] * cb;
        const float4* x0 = (const float4*)xs[r0 + 0];
        const float4* x1 = (const float4*)xs[r0 + 1];
        const float4* x2 = (const float4*)xs[r0 + 2];
        const float4* x3 = (const float4*)xs[r0 + 3];
#pragma unroll
        for (int q4 = 0; q4 < 16; q4++) {
            float w0 = wlds[q4 * 4 + 0][j], w1 = wlds[q4 * 4 + 1][j];
            float w2 = wlds[q4 * 4 + 2][j], w3 = wlds[q4 * 4 + 3][j];
            float4 v0 = x0[q4]; a0 += v0.x * w0 + v0.y * w1 + v0.z * w2 + v0.w * w3;
            float4 v1 = x1[q4]; a1 += v1.x * w0 + v1.y * w1 + v1.z * w2 + v1.w * w3;
            float4 v2 = x2[q4]; a2 += v2.x * w0 + v2.y * w1 + v2.z * w2 + v2.w * w3;
            float4 v3 = x3[q4]; a3 += v3.x * w0 + v3.y * w1 + v3.z * w2 + v3.w * w3;
        }
        a0 = fmaxf(a0, 0.f); a1 = fmaxf(a1, 0.f);
        a2 = fmaxf(a2, 0.f); a3 = fmaxf(a3, 0.f);
        if (last) {
            hout[(nb + 0) * 64 + j] = a0;
            hout[(nb + 1) * 64 + j] = a1;
            hout[(nb + 2) * 64 + j] = a2;
            hout[(nb + 3) * 64 + j] = a3;
        } else {
            uout[(nb + 0) * 64 + j] = __float2half_rn(a0 * dvals[0]);
            uout[(nb + 1) * 64 + j] = __float2half_rn(a1 * dvals[1]);
            uout[(nb + 2) * 64 + j] = __float2half_rn(a2 * dvals[2]);
            uout[(nb + 3) * 64 + j] = __float2half_rn(a3 * dvals[3]);
        }
        if (do_stats) {
            s_sum += a0 + a1 + a2 + a3;
            s_sq += a0 * a0 + a1 * a1 + a2 * a2 + a3 * a3;
        }
    }
    if (do_stats) {
        __syncthreads();
        xs[wid][j] = s_sum;
        xs[4 + wid][j] = s_sq;
        __syncthreads();
        if (t < 64) {
            atomicAdd(&sums_out[t], xs[0][t] + xs[1][t] + xs[2][t] + xs[3][t]);
            atomicAdd(&sums_out[64 + t], xs[4][t] + xs[5][t] + xs[6][t] + xs[7][t]);
        }
    }
}

// ---------------- global_add_pool: 4 blocks per graph, atomic partials into zeroed hg ----------------

__global__ __launch_bounds__(256) void k_pool(const float* __restrict__ h, const int* __restrict__ batch,
                       float* __restrict__ hg) {
    int g = blockIdx.x >> 2, q3 = blockIdx.x & 3;
    int lo = 0, hi = N_NODES;
    while (lo < hi) { int m = (lo + hi) >> 1; if (batch[m] < g) lo = m + 1; else hi = m; }
    int start = lo;
    lo = start; hi = N_NODES;
    while (lo < hi) { int m = (lo + hi) >> 1; if (batch[m] < g + 1) lo = m + 1; else hi = m; }
    int end = lo;
    int len = end - start;
    int c0 = start + ((len * q3) >> 2);
    int c1 = start + ((len * (q3 + 1)) >> 2);
    int c = threadIdx.x & 63, rg = threadIdx.x >> 6;
    float s = 0.f;
    for (int r = c0 + rg; r < c1; r += 4) s += h[r * 64 + c];
    __shared__ float ls[4][64];
    ls[rg][c] = s;
    __syncthreads();
    if (rg == 0) atomicAdd(&hg[g * 64 + c], ls[0][c] + ls[1][c] + ls[2][c] + ls[3][c]);
}

// ---------------- tail: BN-fc stats from hg -> BN -> FC+relu -> BN -> classifier -> log_softmax ----------------

__global__ __launch_bounds__(512) void k_tail(const float* __restrict__ hg_in,
                       const float* __restrict__ g1, const float* __restrict__ b1,
                       const float* __restrict__ Wfc, const float* __restrict__ bfc,
                       const float* __restrict__ g2, const float* __restrict__ b2,
                       const float* __restrict__ Wcls, const float* __restrict__ bcls,
                       float* __restrict__ out) {
    __shared__ float hgn[8192];
    __shared__ float h2[8192];
    __shared__ float red[2][8][64];
    __shared__ float a[64], cc[64];
    __shared__ float Wc[640];
    __shared__ float logits[1280];
    __shared__ float lse[128];
    int t = threadIdx.x;
    int j = t & 63;
    int w = t >> 6;

    // BN-fc stats over the 128 pooled rows (computed in-kernel)
    {
        float su = 0.f, sq = 0.f;
#pragma unroll
        for (int gg = 0; gg < 16; gg++) {
            float v = hg_in[(w * 16 + gg) * 64 + j];
            su += v; sq += v * v;
        }
        red[0][w][j] = su; red[1][w][j] = sq;
    }
    for (int i = t; i < 640; i += 512) Wc[i] = Wcls[i];
    __syncthreads();
    if (t < 64) {
        float su = 0.f, sq = 0.f;
#pragma unroll
        for (int k = 0; k < 8; k++) { su += red[0][k][t]; sq += red[1][k][t]; }
        float mu = su * (1.f / 128.f);
        float var = sq * (1.f / 128.f) - mu * mu;
        float av = g1[t] * rsqrtf(var + EPSBN);
        a[t] = av; cc[t] = b1[t] - mu * av;
    }
    __syncthreads();
    for (int i = t; i < 8192; i += 512) hgn[i] = hg_in[i] * a[i & 63] + cc[i & 63];

    float wreg[64];
#pragma unroll
    for (int q = 0; q < 64; q++) wreg[q] = Wfc[q * 64 + j];
    float bj = bfc[j];
    __syncthreads();

    float acc[16];
#pragma unroll
    for (int r = 0; r < 16; r++) acc[r] = bj;
    const float4* hgn4 = (const float4*)hgn;
#pragma unroll
    for (int q4 = 0; q4 < 16; q4++) {
#pragma unroll
        for (int r = 0; r < 16; r++) {
            float4 hv = hgn4[(w * 16 + r) * 16 + q4];
            acc[r] += hv.x * wreg[q4 * 4 + 0] + hv.y * wreg[q4 * 4 + 1]
                    + hv.z * wreg[q4 * 4 + 2] + hv.w * wreg[q4 * 4 + 3];
        }
    }
    float s = 0.f, s2 = 0.f;
#pragma unroll
    for (int r = 0; r < 16; r++) {
        float v = fmaxf(acc[r], 0.f);
        h2[(w * 16 + r) * 64 + j] = v;
        s += v; s2 += v * v;
    }
    red[0][w][j] = s; red[1][w][j] = s2;
    __syncthreads();

    if (t < 64) {
        float su = 0.f, sq = 0.f;
#pragma unroll
        for (int k = 0; k < 8; k++) { su += red[0][k][t]; sq += red[1][k][t]; }
        float mu = su * (1.f / 128.f);
        float var = sq * (1.f / 128.f) - mu * mu;
        float av = g2[t] * rsqrtf(var + EPSBN);
        a[t] = av; cc[t] = b2[t] - mu * av;
    }
    __syncthreads();
    for (int i = t; i < 8192; i += 512) h2[i] = h2[i] * a[i & 63] + cc[i & 63];
    __syncthreads();

    for (int idx = t; idx < 1280; idx += 512) {
        int row = idx / 10, o = idx - row * 10;
        float v = bcls[o];
#pragma unroll
        for (int q = 0; q < 64; q++) v += h2[row * 64 + q] * Wc[q * 10 + o];
        logits[idx] = v;
    }
    __syncthreads();
    if (t < 128) {
        float mx = -1e30f;
#pragma unroll
        for (int o = 0; o < 10; o++) mx = fmaxf(mx, logits[t * 10 + o]);
        float se = 0.f;
#pragma unroll
        for (int o = 0; o < 10; o++) se += expf(logits[t * 10 + o] - mx);
        lse[t] = mx + logf(se);
    }
    __syncthreads();
    for (int idx = t; idx < 1280; idx += 512) out[idx] = logits[idx] - lse[idx / 10];
}

// ---------------- launcher ----------------

extern "C" void kernel_launch(void* const* d_in, const int* in_sizes, int n_in,
                              void* d_out, int out_size, void* d_ws, size_t ws_size,
                              hipStream_t stream) {
    const float* x         = (const float*)d_in[0];
    const int*   ei        = (const int*)  d_in[1];
    const int*   batch     = (const int*)  d_in[2];
    const float* bn_feat_g = (const float*)d_in[3];
    const float* bn_feat_b = (const float*)d_in[4];
    const float* W_feat    = (const float*)d_in[5];
    const float* b_feat    = (const float*)d_in[6];
    const float* conv_bn_g = (const float*)d_in[7];
    const float* conv_bn_b = (const float*)d_in[8];
    const float* conv_W    = (const float*)d_in[9];
    const float* conv_b    = (const float*)d_in[10];
    const float* bn_fc_g   = (const float*)d_in[11];
    const float* bn_fc_b   = (const float*)d_in[12];
    const float* W_fc      = (const float*)d_in[13];
    const float* b_fc      = (const float*)d_in[14];
    const float* bn_hid_g  = (const float*)d_in[15];
    const float* bn_hid_b  = (const float*)d_in[16];
    const float* W_cls     = (const float*)d_in[17];
    const float* b_cls     = (const float*)d_in[18];
    float* out = (float*)d_out;

    float* ws    = (float*)d_ws;
    float* hbuf  = ws;                          // 6,400,000 f (final layer h only)
    __half* u_a  = (__half*)(ws + 6400000);     // 6.4M halves
    __half* u_b  = (__half*)(ws + 9600000);     // 6.4M halves
    float* dis   = ws + 12800000;               // 100,000 f
    float* sigma = ws + 12900000;               // 100,000 f
    float* Wt    = ws + 13000000;               // 4096 f
    float* bt    = Wt + 4096;                   // 64 f
    float* hg    = bt + 64;                     // 8192 f
    float* sums  = hg + 8192;                   // 640 f (sx, s0, s1, s2)
    int*   cnt   = (int*)(sums + 640);          // 100,000 i
    int*   ecsr  = cnt + 100000;                // 6,400,000 i
    int*   deg   = (int*)u_b;                   // 100,000 i scratch; dead before u_b written

    float* sx = sums;
    float* s0 = sums + 128;
    float* s1 = sums + 256;
    float* s2 = sums + 384;

    const int* srcp = ei;
    const int* dstp = ei + N_EDGES;

    // zero hg + sums + cnt in one contiguous memset; deg lives in u_b scratch
    hipMemsetAsync(hg, 0, (8192 + 640 + 100000) * sizeof(float), stream);
    hipMemsetAsync(deg, 0, 100000 * sizeof(int), stream);

    // fused pipeline: [build || stats] -> [dis + fold] -> [gemm2 || sigma]
    k_build_stats<<<2560, 256, 0, stream>>>(srcp, dstp, cnt, deg, ecsr, x, sx);
    k_dis_fold<<<392, 256, 0, stream>>>(deg, dis, sx, bn_feat_g, bn_feat_b,
                                        W_feat, b_feat, Wt, bt);
    k_sigma_gemm2<<<3072, 256, 0, stream>>>(x, Wt, bt, dis, u_a, s0, cnt, ecsr, sigma);

    // 3 GCN conv layers: aggemm with in-kernel BN fold + sigma correction, u double-buffered
    k_aggemm<<<2048, 256, 0, stream>>>(u_a, dis, sigma, cnt, ecsr,
                                       s0, conv_bn_g + 0, conv_bn_b + 0,
                                       conv_W + 0, conv_b + 0,
                                       u_b, nullptr, 0, s1, 1);
    k_aggemm<<<2048, 256, 0, stream>>>(u_b, dis, sigma, cnt, ecsr,
                                       s1, conv_bn_g + 64, conv_bn_b + 64,
                                       conv_W + 4096, conv_b + 64,
                                       u_a, nullptr, 0, s2, 1);
    k_aggemm<<<2048, 256, 0, stream>>>(u_a, dis, sigma, cnt, ecsr,
                                       s2, conv_bn_g + 128, conv_bn_b + 128,
                                       conv_W + 8192, conv_b + 128,
                                       nullptr, hbuf, 1, nullptr, 0);

    // pooling + tail (BN-fc stats computed inside k_tail)
    k_pool<<<4 * GRAPHS, 256, 0, stream>>>(hbuf, batch, hg);
    k_tail<<<1, 512, 0, stream>>>(hg, bn_fc_g, bn_fc_b, W_fc, b_fc,
                                  bn_hid_g, bn_hid_b, W_cls, b_cls, out);
}

// Round 15
// 510.803 us; speedup vs baseline: 1.1119x; 1.0174x over previous
//
#include <hip/hip_runtime.h>
#include <hip/hip_fp16.h>

#define N_NODES 100000
#define N_EDGES 1200000
#define GRAPHS 128
#define EPSBN 1e-5f
#define NSHARD 8
#define SH_NODES 12500   // N_NODES / NSHARD exact

// ---------------- fused: XCD-sharded CSR build (blocks 0..2047) + BN stats on x (2048..2559) ----

__global__ __launch_bounds__(256) void k_build_stats(const int* __restrict__ src,
                                                     const int* __restrict__ dst,
                                                     int* __restrict__ cnt,
                                                     int* __restrict__ deg,
                                                     int* __restrict__ ecsr,
                                                     const float* __restrict__ x,
                                                     float* __restrict__ sums) {
    int t = threadIdx.x;
    if (blockIdx.x < 2048) {
        int shard = blockIdx.x & (NSHARD - 1);
        int lo = shard * SH_NODES, hi = lo + SH_NODES;
        for (int e = (blockIdx.x >> 3) * 256 + t; e < N_EDGES; e += 65536) {
            int s = __builtin_nontemporal_load(&src[e]);
            int d = __builtin_nontemporal_load(&dst[e]);
            if (s >= lo && s < hi) atomicAdd(&deg[s], 1);
            if (d >= lo && d < hi) {
                int p = atomicAdd(&cnt[d], 1);
                ecsr[(d << 6) + p] = s;
            }
        }
    } else {
        int bid = blockIdx.x - 2048;   // 0..511
        const float4* x4 = (const float4*)x;
        int q = t & 15, rg = t >> 4;
        float4 s = {0.f, 0.f, 0.f, 0.f}, s2 = {0.f, 0.f, 0.f, 0.f};
        for (int r = bid * 16 + rg; r < N_NODES; r += 512 * 16) {
            float4 v = x4[r * 16 + q];
            s.x += v.x; s.y += v.y; s.z += v.z; s.w += v.w;
            s2.x += v.x * v.x; s2.y += v.y * v.y; s2.z += v.z * v.z; s2.w += v.w * v.w;
        }
        __shared__ float red[2][16][64];
        red[0][rg][q * 4 + 0] = s.x;  red[0][rg][q * 4 + 1] = s.y;
        red[0][rg][q * 4 + 2] = s.z;  red[0][rg][q * 4 + 3] = s.w;
        red[1][rg][q * 4 + 0] = s2.x; red[1][rg][q * 4 + 1] = s2.y;
        red[1][rg][q * 4 + 2] = s2.z; red[1][rg][q * 4 + 3] = s2.w;
        __syncthreads();
        if (t < 64) {
            float a = 0.f, b = 0.f;
#pragma unroll
            for (int k = 0; k < 16; k++) { a += red[0][k][t]; b += red[1][k][t]; }
            atomicAdd(&sums[t], a);
            atomicAdd(&sums[64 + t], b);
        }
    }
}

// ---------------- fused: dis (blocks 0..390) + BN fold for feature layer (block 391) ----------------

__global__ __launch_bounds__(256) void k_dis_fold(const int* __restrict__ deg,
                       float* __restrict__ dis,
                       const float* __restrict__ sums, const float* __restrict__ g,
                       const float* __restrict__ b, const float* __restrict__ W,
                       const float* __restrict__ bias_in,
                       float* __restrict__ Wout, float* __restrict__ bout) {
    int t = threadIdx.x;
    if (blockIdx.x < 391) {
        int i = blockIdx.x * 256 + t;
        if (i < N_NODES) dis[i] = rsqrtf((float)deg[i] + 1.0f);   // +1 self-loop
    } else {
        __shared__ float a[64], cc[64];
        if (t < 64) {
            float mu = sums[t] * (1.0f / N_NODES);
            float var = sums[64 + t] * (1.0f / N_NODES) - mu * mu;
            float av = g[t] * rsqrtf(var + EPSBN);
            a[t] = av;
            cc[t] = b[t] - mu * av;
        }
        __syncthreads();
        for (int i = t; i < 4096; i += 256) Wout[i] = a[i >> 6] * W[i];
        if (t < 64) {
            float acc = bias_in[t];
            for (int k = 0; k < 64; k++) acc += cc[k] * W[k * 64 + t];
            bout[t] = acc;
        }
    }
}

// ---------------- fused: feature GEMM (blocks 0..2047) + sigma (2048..3071) ----------------

__global__ __launch_bounds__(256, 4) void k_sigma_gemm2(const float* __restrict__ X,
                        const float* __restrict__ W,
                        const float* __restrict__ bias, const float* __restrict__ dis,
                        __half* __restrict__ U, float* __restrict__ sums,
                        const int* __restrict__ cnt, const int* __restrict__ ecsr,
                        float* __restrict__ sigma) {
    __shared__ float wlds[64][64];
    __shared__ float xs[16][64];
    int t = threadIdx.x;
    if (blockIdx.x < 2048) {
        int j = t & 63;
        int rg = t >> 6;
        for (int i = t; i < 4096; i += 256) wlds[i >> 6][i & 63] = W[i];
        float bj = bias[j];
        __syncthreads();
        float s_sum = 0.f, s_sq = 0.f;
        for (int base = blockIdx.x * 16; base < N_NODES; base += 2048 * 16) {
            ((float4*)xs)[t] = ((const float4*)(X + base * 64))[t];   // wave-private rows
            int r0 = rg * 4;
            float a0 = bj, a1 = bj, a2 = bj, a3 = bj;
            const float4* x0 = (const float4*)xs[r0 + 0];
            const float4* x1 = (const float4*)xs[r0 + 1];
            const float4* x2 = (const float4*)xs[r0 + 2];
            const float4* x3 = (const float4*)xs[r0 + 3];
#pragma unroll
            for (int q4 = 0; q4 < 16; q4++) {
                float w0 = wlds[q4 * 4 + 0][j], w1 = wlds[q4 * 4 + 1][j];
                float w2 = wlds[q4 * 4 + 2][j], w3 = wlds[q4 * 4 + 3][j];
                float4 v0 = x0[q4]; a0 += v0.x * w0 + v0.y * w1 + v0.z * w2 + v0.w * w3;
                float4 v1 = x1[q4]; a1 += v1.x * w0 + v1.y * w1 + v1.z * w2 + v1.w * w3;
                float4 v2 = x2[q4]; a2 += v2.x * w0 + v2.y * w1 + v2.z * w2 + v2.w * w3;
                float4 v3 = x3[q4]; a3 += v3.x * w0 + v3.y * w1 + v3.z * w2 + v3.w * w3;
            }
            a0 = fmaxf(a0, 0.f); a1 = fmaxf(a1, 0.f);
            a2 = fmaxf(a2, 0.f); a3 = fmaxf(a3, 0.f);
            int nb = base + r0;
            U[(nb + 0) * 64 + j] = __float2half_rn(a0 * dis[nb + 0]);
            U[(nb + 1) * 64 + j] = __float2half_rn(a1 * dis[nb + 1]);
            U[(nb + 2) * 64 + j] = __float2half_rn(a2 * dis[nb + 2]);
            U[(nb + 3) * 64 + j] = __float2half_rn(a3 * dis[nb + 3]);
            s_sum += a0 + a1 + a2 + a3;
            s_sq += a0 * a0 + a1 * a1 + a2 * a2 + a3 * a3;
        }
        __syncthreads();
        xs[rg][j] = s_sum;
        xs[4 + rg][j] = s_sq;
        __syncthreads();
        if (t < 64) {
            atomicAdd(&sums[t], xs[0][t] + xs[1][t] + xs[2][t] + xs[3][t]);
            atomicAdd(&sums[64 + t], xs[4][t] + xs[5][t] + xs[6][t] + xs[7][t]);
        }
    } else {
        int bid = blockIdx.x - 2048;   // 0..1023
        int lane = t & 63;
        int wid = t >> 6;
        for (int node = bid * 4 + wid; node < N_NODES; node += 1024 * 4) {
            int m = cnt[node];
            int sraw = ecsr[(node << 6) + lane];
            float dd = dis[node];
            int sL = (lane < m) ? sraw : 0;
            float v = (lane < m) ? dis[sL] : 0.f;
#pragma unroll
            for (int d = 1; d <= 32; d <<= 1) v += __shfl_xor(v, d, 64);
            if (lane == 0) sigma[node] = dd * (v + dd);
        }
    }
}

// ---------------- fused agg+GEMM with in-kernel BN fold (sigma correction) ----------------
// Phase A: 16-slot row-paired predicated gathers (proven optimum: 8 serial regresses,
// 32 slots regresses on L2 BW). Epilogue: !last -> u fp16; last -> POOLED atomic
// accumulation into hg (replaces 25.6MB h write + 25.6MB pool re-read + k_pool launch).
// batch is sorted -> wave's 4 rows usually one graph -> 1 non-returning atomic/lane/tile.

__global__ __launch_bounds__(256, 4) void k_aggemm(const __half* __restrict__ u,
                        const float* __restrict__ dis, const float* __restrict__ sigma,
                        const int* __restrict__ cnt, const int* __restrict__ ecsr,
                        const float* __restrict__ sums_in, const float* __restrict__ bng,
                        const float* __restrict__ bnb,
                        const float* __restrict__ W, const float* __restrict__ bias,
                        __half* __restrict__ uout,
                        const int* __restrict__ batch, float* __restrict__ hg, int last,
                        float* __restrict__ sums_out, int do_stats) {
    const __half2* u2 = (const __half2*)u;
    int t = threadIdx.x;
    int j = t & 63;           // lane; also output column in GEMM phase
    int wid = t >> 6;
    int g = j >> 5, c = j & 31;
    __shared__ float wlds[64][64];
    __shared__ float xs[16][64];   // wave w owns rows 4w..4w+3 (wave-private); prologue: xs[0]=aa, xs[1]=ccs
    if (t < 64) {
        float mu = sums_in[t] * (1.0f / N_NODES);
        float var = sums_in[64 + t] * (1.0f / N_NODES) - mu * mu;
        float av = bng[t] * rsqrtf(var + EPSBN);
        xs[0][t] = av;                 // aa
        xs[1][t] = bnb[t] - mu * av;   // ccs
    }
    __syncthreads();
    for (int i = t; i < 4096; i += 256) wlds[i >> 6][i & 63] = W[i] * xs[0][i >> 6];
    float cb = 0.f;
#pragma unroll 8
    for (int q = 0; q < 64; q++) cb += xs[1][q] * W[q * 64 + j];
    float bj = bias[j];
    __syncthreads();
    float s_sum = 0.f, s_sq = 0.f;
    for (int base = blockIdx.x * 16; base < N_NODES; base += gridDim.x * 16) {
        int r0 = wid * 4;
        int nb = base + r0;
        // ---- hoisted independent loads for all 4 rows ----
        int mm[4], srw[4];
        float dvals[4], svals[4];
        __half2 selfs[4];
#pragma unroll
        for (int r = 0; r < 4; r++) {
            mm[r] = cnt[nb + r];
            srw[r] = ecsr[((nb + r) << 6) + j];
            dvals[r] = dis[nb + r];
            svals[r] = sigma[nb + r];
            selfs[r] = u2[(nb + r) * 32 + c];
        }
        // ---- phase A: row-paired interleaved 16-slot gathers ----
#pragma unroll
        for (int rp = 0; rp < 2; rp++) {
            int ra = 2 * rp, rb = 2 * rp + 1;
            int ma = mm[ra], mb = mm[rb];
            int sLa = (j < ma) ? srw[ra] : 0;
            int sLb = (j < mb) ? srw[rb] : 0;
            float axa = 0.f, aya = 0.f, axb = 0.f, ayb = 0.f;
#pragma unroll
            for (int k = 0; k < 8; k++) {
                int e = 2 * k + g;
                int sEa = __shfl(sLa, e, 64);
                int sEb = __shfl(sLb, e, 64);
                float wa = (e < ma) ? 1.0f : 0.0f;
                float wb = (e < mb) ? 1.0f : 0.0f;
                float2 fa = __half22float2(u2[sEa * 32 + c]);
                float2 fb = __half22float2(u2[sEb * 32 + c]);
                axa += wa * fa.x; aya += wa * fa.y;
                axb += wb * fb.x; ayb += wb * fb.y;
            }
            if (ma > 16) {
                for (int e = 16 + g; e < ma; e += 2) {
                    int sE = __shfl(sLa, e, 64);
                    float2 f = __half22float2(u2[sE * 32 + c]);
                    axa += f.x; aya += f.y;
                }
            }
            if (mb > 16) {
                for (int e = 16 + g; e < mb; e += 2) {
                    int sE = __shfl(sLb, e, 64);
                    float2 f = __half22float2(u2[sE * 32 + c]);
                    axb += f.x; ayb += f.y;
                }
            }
            axa += __shfl_xor(axa, 32, 64); aya += __shfl_xor(aya, 32, 64);
            axb += __shfl_xor(axb, 32, 64); ayb += __shfl_xor(ayb, 32, 64);
            if (g == 0) {
                float2 sfa = __half22float2(selfs[ra]);
                float2 sfb = __half22float2(selfs[rb]);
                float da = dvals[ra], db = dvals[rb];
                xs[r0 + ra][2 * c + 0] = da * (axa + sfa.x);
                xs[r0 + ra][2 * c + 1] = da * (aya + sfa.y);
                xs[r0 + rb][2 * c + 0] = db * (axb + sfb.x);
                xs[r0 + rb][2 * c + 1] = db * (ayb + sfb.y);
            }
        }
        // ---- phase B: GEMM + sigma correction (wave-private LDS, W from LDS) ----
        float a0 = bj + svals[0] * cb, a1 = bj + svals[1] * cb;
        float a2 = bj + svals[2] * cb, a3 = bj + svals[3] * cb;
        const float4* x0 = (const float4*)xs[r0 + 0];
        const float4* x1 = (const float4*)xs[r0 + 1];
        const float4* x2 = (const float4*)xs[r0 + 2];
        const float4* x3 = (const float4*)xs[r0 + 3];
#pragma unroll
        for (int q4 = 0; q4 < 16; q4++) {
            float w0 = wlds[q4 * 4 + 0][j], w1 = wlds[q4 * 4 + 1][j];
            float w2 = wlds[q4 * 4 + 2][j], w3 = wlds[q4 * 4 + 3][j];
            float4 v0 = x0[q4]; a0 += v0.x * w0 + v0.y * w1 + v0.z * w2 + v0.w * w3;
            float4 v1 = x1[q4]; a1 += v1.x * w0 + v1.y * w1 + v1.z * w2 + v1.w * w3;
            float4 v2 = x2[q4]; a2 += v2.x * w0 + v2.y * w1 + v2.z * w2 + v2.w * w3;
            float4 v3 = x3[q4]; a3 += v3.x * w0 + v3.y * w1 + v3.z * w2 + v3.w * w3;
        }
        a0 = fmaxf(a0, 0.f); a1 = fmaxf(a1, 0.f);
        a2 = fmaxf(a2, 0.f); a3 = fmaxf(a3, 0.f);
        if (last) {
            // fused global_add_pool: batch sorted; fast path = whole wave-tile in one graph
            int b0 = batch[nb + 0], b3 = batch[nb + 3];
            if (b0 == b3) {
                atomicAdd(&hg[b0 * 64 + j], a0 + a1 + a2 + a3);
            } else {
                int b1v = batch[nb + 1], b2v = batch[nb + 2];
                atomicAdd(&hg[b0 * 64 + j], a0);
                atomicAdd(&hg[b1v * 64 + j], a1);
                atomicAdd(&hg[b2v * 64 + j], a2);
                atomicAdd(&hg[b3 * 64 + j], a3);
            }
        } else {
            uout[(nb + 0) * 64 + j] = __float2half_rn(a0 * dvals[0]);
            uout[(nb + 1) * 64 + j] = __float2half_rn(a1 * dvals[1]);
            uout[(nb + 2) * 64 + j] = __float2half_rn(a2 * dvals[2]);
            uout[(nb + 3) * 64 + j] = __float2half_rn(a3 * dvals[3]);
        }
        if (do_stats) {
            s_sum += a0 + a1 + a2 + a3;
            s_sq += a0 * a0 + a1 * a1 + a2 * a2 + a3 * a3;
        }
    }
    if (do_stats) {
        __syncthreads();
        xs[wid][j] = s_sum;
        xs[4 + wid][j] = s_sq;
        __syncthreads();
        if (t < 64) {
            atomicAdd(&sums_out[t], xs[0][t] + xs[1][t] + xs[2][t] + xs[3][t]);
            atomicAdd(&sums_out[64 + t], xs[4][t] + xs[5][t] + xs[6][t] + xs[7][t]);
        }
    }
}

// ---------------- tail: BN-fc stats from hg -> BN -> FC+relu -> BN -> classifier -> log_softmax ----------------

__global__ __launch_bounds__(512) void k_tail(const float* __restrict__ hg_in,
                       const float* __restrict__ g1, const float* __restrict__ b1,
                       const float* __restrict__ Wfc, const float* __restrict__ bfc,
                       const float* __restrict__ g2, const float* __restrict__ b2,
                       const float* __restrict__ Wcls, const float* __restrict__ bcls,
                       float* __restrict__ out) {
    __shared__ float hgn[8192];
    __shared__ float h2[8192];
    __shared__ float red[2][8][64];
    __shared__ float a[64], cc[64];
    __shared__ float Wc[640];
    __shared__ float logits[1280];
    __shared__ float lse[128];
    int t = threadIdx.x;
    int j = t & 63;
    int w = t >> 6;

    // BN-fc stats over the 128 pooled rows (computed in-kernel)
    {
        float su = 0.f, sq = 0.f;
#pragma unroll
        for (int gg = 0; gg < 16; gg++) {
            float v = hg_in[(w * 16 + gg) * 64 + j];
            su += v; sq += v * v;
        }
        red[0][w][j] = su; red[1][w][j] = sq;
    }
    for (int i = t; i < 640; i += 512) Wc[i] = Wcls[i];
    __syncthreads();
    if (t < 64) {
        float su = 0.f, sq = 0.f;
#pragma unroll
        for (int k = 0; k < 8; k++) { su += red[0][k][t]; sq += red[1][k][t]; }
        float mu = su * (1.f / 128.f);
        float var = sq * (1.f / 128.f) - mu * mu;
        float av = g1[t] * rsqrtf(var + EPSBN);
        a[t] = av; cc[t] = b1[t] - mu * av;
    }
    __syncthreads();
    for (int i = t; i < 8192; i += 512) hgn[i] = hg_in[i] * a[i & 63] + cc[i & 63];

    float wreg[64];
#pragma unroll
    for (int q = 0; q < 64; q++) wreg[q] = Wfc[q * 64 + j];
    float bj = bfc[j];
    __syncthreads();

    float acc[16];
#pragma unroll
    for (int r = 0; r < 16; r++) acc[r] = bj;
    const float4* hgn4 = (const float4*)hgn;
#pragma unroll
    for (int q4 = 0; q4 < 16; q4++) {
#pragma unroll
        for (int r = 0; r < 16; r++) {
            float4 hv = hgn4[(w * 16 + r) * 16 + q4];
            acc[r] += hv.x * wreg[q4 * 4 + 0] + hv.y * wreg[q4 * 4 + 1]
                    + hv.z * wreg[q4 * 4 + 2] + hv.w * wreg[q4 * 4 + 3];
        }
    }
    float s = 0.f, s2 = 0.f;
#pragma unroll
    for (int r = 0; r < 16; r++) {
        float v = fmaxf(acc[r], 0.f);
        h2[(w * 16 + r) * 64 + j] = v;
        s += v; s2 += v * v;
    }
    red[0][w][j] = s; red[1][w][j] = s2;
    __syncthreads();

    if (t < 64) {
        float su = 0.f, sq = 0.f;
#pragma unroll
        for (int k = 0; k < 8; k++) { su += red[0][k][t]; sq += red[1][k][t]; }
        float mu = su * (1.f / 128.f);
        float var = sq * (1.f / 128.f) - mu * mu;
        float av = g2[t] * rsqrtf(var + EPSBN);
        a[t] = av; cc[t] = b2[t] - mu * av;
    }
    __syncthreads();
    for (int i = t; i < 8192; i += 512) h2[i] = h2[i] * a[i & 63] + cc[i & 63];
    __syncthreads();

    for (int idx = t; idx < 1280; idx += 512) {
        int row = idx / 10, o = idx - row * 10;
        float v = bcls[o];
#pragma unroll
        for (int q = 0; q < 64; q++) v += h2[row * 64 + q] * Wc[q * 10 + o];
        logits[idx] = v;
    }
    __syncthreads();
    if (t < 128) {
        float mx = -1e30f;
#pragma unroll
        for (int o = 0; o < 10; o++) mx = fmaxf(mx, logits[t * 10 + o]);
        float se = 0.f;
#pragma unroll
        for (int o = 0; o < 10; o++) se += expf(logits[t * 10 + o] - mx);
        lse[t] = mx + logf(se);
    }
    __syncthreads();
    for (int idx = t; idx < 1280; idx += 512) out[idx] = logits[idx] - lse[idx / 10];
}

// ---------------- launcher ----------------

extern "C" void kernel_launch(void* const* d_in, const int* in_sizes, int n_in,
                              void* d_out, int out_size, void* d_ws, size_t ws_size,
                              hipStream_t stream) {
    const float* x         = (const float*)d_in[0];
    const int*   ei        = (const int*)  d_in[1];
    const int*   batch     = (const int*)  d_in[2];
    const float* bn_feat_g = (const float*)d_in[3];
    const float* bn_feat_b = (const float*)d_in[4];
    const float* W_feat    = (const float*)d_in[5];
    const float* b_feat    = (const float*)d_in[6];
    const float* conv_bn_g = (const float*)d_in[7];
    const float* conv_bn_b = (const float*)d_in[8];
    const float* conv_W    = (const float*)d_in[9];
    const float* conv_b    = (const float*)d_in[10];
    const float* bn_fc_g   = (const float*)d_in[11];
    const float* bn_fc_b   = (const float*)d_in[12];
    const float* W_fc      = (const float*)d_in[13];
    const float* b_fc      = (const float*)d_in[14];
    const float* bn_hid_g  = (const float*)d_in[15];
    const float* bn_hid_b  = (const float*)d_in[16];
    const float* W_cls     = (const float*)d_in[17];
    const float* b_cls     = (const float*)d_in[18];
    float* out = (float*)d_out;

    float* ws    = (float*)d_ws;
    float* hbuf  = ws;                          // scratch (unused after pool fusion)
    __half* u_a  = (__half*)(ws + 6400000);     // 6.4M halves
    __half* u_b  = (__half*)(ws + 9600000);     // 6.4M halves
    float* dis   = ws + 12800000;               // 100,000 f
    float* sigma = ws + 12900000;               // 100,000 f
    float* Wt    = ws + 13000000;               // 4096 f
    float* bt    = Wt + 4096;                   // 64 f
    float* hg    = bt + 64;                     // 8192 f
    float* sums  = hg + 8192;                   // 640 f (sx, s0, s1, s2)
    int*   cnt   = (int*)(sums + 640);          // 100,000 i
    int*   ecsr  = cnt + 100000;                // 6,400,000 i
    int*   deg   = (int*)u_b;                   // 100,000 i scratch; dead before u_b written

    float* sx = sums;
    float* s0 = sums + 128;
    float* s1 = sums + 256;
    float* s2 = sums + 384;

    const int* srcp = ei;
    const int* dstp = ei + N_EDGES;

    // zero hg + sums + cnt in one contiguous memset; deg lives in u_b scratch
    hipMemsetAsync(hg, 0, (8192 + 640 + 100000) * sizeof(float), stream);
    hipMemsetAsync(deg, 0, 100000 * sizeof(int), stream);

    // fused pipeline: [build || stats] -> [dis + fold] -> [gemm2 || sigma]
    k_build_stats<<<2560, 256, 0, stream>>>(srcp, dstp, cnt, deg, ecsr, x, sx);
    k_dis_fold<<<392, 256, 0, stream>>>(deg, dis, sx, bn_feat_g, bn_feat_b,
                                        W_feat, b_feat, Wt, bt);
    k_sigma_gemm2<<<3072, 256, 0, stream>>>(x, Wt, bt, dis, u_a, s0, cnt, ecsr, sigma);

    // 3 GCN conv layers; last layer fuses global_add_pool into its epilogue
    k_aggemm<<<2048, 256, 0, stream>>>(u_a, dis, sigma, cnt, ecsr,
                                       s0, conv_bn_g + 0, conv_bn_b + 0,
                                       conv_W + 0, conv_b + 0,
                                       u_b, nullptr, nullptr, 0, s1, 1);
    k_aggemm<<<2048, 256, 0, stream>>>(u_b, dis, sigma, cnt, ecsr,
                                       s1, conv_bn_g + 64, conv_bn_b + 64,
                                       conv_W + 4096, conv_b + 64,
                                       u_a, nullptr, nullptr, 0, s2, 1);
    k_aggemm<<<2048, 256, 0, stream>>>(u_a, dis, sigma, cnt, ecsr,
                                       s2, conv_bn_g + 128, conv_bn_b + 128,
                                       conv_W + 8192, conv_b + 128,
                                       nullptr, batch, hg, 1, nullptr, 0);

    // tail (BN-fc stats computed inside; reads hg only)
    k_tail<<<1, 512, 0, stream>>>(hg, bn_fc_g, bn_fc_b, W_fc, b_fc,
                                  bn_hid_g, bn_hid_b, W_cls, b_cls, out);
}